// Round 6
// baseline (326.643 us; speedup 1.0000x reference)
//
#include <hip/hip_runtime.h>
#include <hip/hip_fp16.h>

// Fused Conv3d(3->16, 3x3x3, VALID) + bias + channel softmax + maxpool(4,4,4)/4.
// x: [512,3,16,32,32] f32, w: [16,3,3,3,3] f32, b: [16] f32
// out: [512,16,3,7,7] f32
//
// R6: switch the conv arithmetic to packed fp16 (v_pk_fma_f16, 2 FLOP/lane)
// and block = (n, ph) covering ALL 12 d positions (3 pd windows) -> 3x weight
// reuse per load. Inputs staged as PRE-SPLATTED half2 in LDS (4B/elem, b32
// conflict-free reads, zero repack). Weights pre-converted to fp16 [tap][c]
// in d_ws, read as uniform-address dwordx4 (vmcnt pipe, L1-resident).
// Grid: 512*7 = 3584 blocks x 128 threads (112 compute: dh 0..3 x wp 0..27).

#define LW 33  // lw stride in half2 units; +1 so dh offsets land on distinct banks

__global__ void wtrans(const float* __restrict__ w, __half* __restrict__ wt) {
  for (int t = threadIdx.x; t < 81 * 16; t += 128) {
    int c = t & 15, tap = t >> 4;
    wt[t] = __float2half(w[c * 81 + tap]);  // wt[tap][c]
  }
}

__global__ __launch_bounds__(128) void conv_sm_pool(
    const float* __restrict__ x, const __half* __restrict__ wt,
    const float* __restrict__ b, float* __restrict__ out) {
  __shared__ __half2 xs[3 * 14 * 6 * LW];   // [cin][ld 0..13][lh 0..5][lw], splatted
  __shared__ float pool[3 * 7 * 16];        // [pd][pw][c]

  const int tid = threadIdx.x;
  const int blk = blockIdx.x;
  const int n  = blk / 7;
  const int ph = blk % 7;

  // ---- stage input: cin 0..2, d 0..13, h 4ph..4ph+5, w 0..31, as splat half2
  const float* xb = x + ((size_t)n * 3 * 16 * 32 * 32) + (size_t)(4 * ph) * 32;
  for (int i = tid; i < 3 * 14 * 6 * 16; i += 128) {   // float2 pairs
    int lw2 = i & 15;
    int rest = i >> 4;            // cin*84 + ld*6 + lh
    int lh = rest % 6;
    int rest2 = rest / 6;
    int ld = rest2 % 14;
    int cin = rest2 / 14;
    const float2 v = *reinterpret_cast<const float2*>(
        &xb[((cin * 16 + ld) * 32 + lh) * 32 + lw2 * 2]);
    __half2* dst = &xs[((cin * 14 + ld) * 6 + lh) * LW + lw2 * 2];
    dst[0] = __float2half2_rn(v.x);   // splat both halves
    dst[1] = __float2half2_rn(v.y);
  }
  for (int i = tid; i < 3 * 7 * 16; i += 128) pool[i] = 0.0f;  // probs > 0
  __syncthreads();

  if (tid < 112) {
    const int dh = tid / 28;      // conv h = 4*ph + dh
    const int wp = tid % 28;      // conv w

    __half2 acc[12][8];           // [d][channel-pair]
#pragma unroll
    for (int c2 = 0; c2 < 8; ++c2) {
      __half2 bb = __halves2half2(__float2half(b[2 * c2]),
                                  __float2half(b[2 * c2 + 1]));
#pragma unroll
      for (int d = 0; d < 12; ++d) acc[d][c2] = bb;
    }

    const float4* wt4 = reinterpret_cast<const float4*>(wt);  // [tap][2] x 4 half2
    for (int cin = 0; cin < 3; ++cin) {
      for (int kh = 0; kh < 3; ++kh) {
        const __half2* xbase = &xs[((cin * 14) * 6 + dh + kh) * LW + wp];
        __half2 in[3][14];
#pragma unroll
        for (int kw = 0; kw < 3; ++kw)
#pragma unroll
          for (int ld = 0; ld < 14; ++ld)
            in[kw][ld] = xbase[(ld * 6) * LW + kw];   // immediate offsets

        const float4* wb = wt4 + (cin * 27 + kh * 3) * 2;
#pragma unroll
        for (int kw = 0; kw < 3; ++kw) {
#pragma unroll
          for (int kr = 0; kr < 3; ++kr) {
            float4 wv0 = wb[(kr * 9 + kw) * 2 + 0];   // ch 0..7, uniform addr
            float4 wv1 = wb[(kr * 9 + kw) * 2 + 1];   // ch 8..15
            const __half2* w0 = reinterpret_cast<const __half2*>(&wv0);
            const __half2* w1 = reinterpret_cast<const __half2*>(&wv1);
#pragma unroll
            for (int c2 = 0; c2 < 4; ++c2) {
#pragma unroll
              for (int d = 0; d < 12; ++d) {
                acc[d][c2]     = __hfma2(in[kw][d + kr], w0[c2], acc[d][c2]);
                acc[d][c2 + 4] = __hfma2(in[kw][d + kr], w1[c2], acc[d][c2 + 4]);
              }
            }
          }
        }
      }
    }

    // ---- per pd window: softmax over 16 ch per d, max over 4 d, pool ----
#pragma unroll
    for (int pd = 0; pd < 3; ++pd) {
      float pm[16];
#pragma unroll
      for (int c = 0; c < 16; ++c) pm[c] = 0.0f;
#pragma unroll
      for (int dd = 0; dd < 4; ++dd) {
        const int d = pd * 4 + dd;
        float y[16];
#pragma unroll
        for (int c2 = 0; c2 < 8; ++c2) {
          float2 f = __half22float2(acc[d][c2]);
          y[2 * c2] = f.x; y[2 * c2 + 1] = f.y;
        }
        float m = y[0];
#pragma unroll
        for (int c = 1; c < 16; ++c) m = fmaxf(m, y[c]);
        float s = 0.0f;
#pragma unroll
        for (int c = 0; c < 16; ++c) { y[c] = __expf(y[c] - m); s += y[c]; }
        float rs = 1.0f / s;
#pragma unroll
        for (int c = 0; c < 16; ++c) pm[c] = fmaxf(pm[c], y[c] * rs);
      }
      // reduce over 4 w-lanes (tid≡lane mod 4, 28%4==0 -> groups aligned)
#pragma unroll
      for (int c = 0; c < 16; ++c) {
        pm[c] = fmaxf(pm[c], __shfl_xor(pm[c], 1, 64));
        pm[c] = fmaxf(pm[c], __shfl_xor(pm[c], 2, 64));
      }
      if ((wp & 3) == 0) {
        const int pw = wp >> 2;
#pragma unroll
        for (int c = 0; c < 16; ++c)
          atomicMax(reinterpret_cast<int*>(&pool[(pd * 7 + pw) * 16 + c]),
                    __float_as_int(pm[c]));  // probs > 0
      }
    }
  }
  __syncthreads();

  // out[n][c][pd][ph][pw]
  for (int i = tid; i < 3 * 7 * 16; i += 128) {
    int c = i & 15;
    int q = i >> 4;
    int pd = q / 7, pw = q % 7;
    out[(((size_t)n * 16 + c) * 3 + pd) * 49 + (size_t)ph * 7 + pw] =
        pool[(pd * 7 + pw) * 16 + c];
  }
}

extern "C" void kernel_launch(void* const* d_in, const int* in_sizes, int n_in,
                              void* d_out, int out_size, void* d_ws, size_t ws_size,
                              hipStream_t stream) {
  const float* x = (const float*)d_in[0];
  const float* w = (const float*)d_in[1];
  const float* b = (const float*)d_in[2];
  float* out = (float*)d_out;
  __half* wt = (__half*)d_ws;   // 81*16*2 = 2592 B scratch
  (void)in_sizes; (void)n_in; (void)out_size; (void)ws_size;
  hipLaunchKernelGGL(wtrans, dim3(1), dim3(128), 0, stream, w, wt);
  hipLaunchKernelGGL(conv_sm_pool, dim3(512 * 7), dim3(128), 0, stream,
                     x, wt, b, out);
}

// Round 7
// 285.185 us; speedup vs baseline: 1.1454x; 1.1454x over previous
//
#include <hip/hip_runtime.h>
#include <hip/hip_fp16.h>

// Fused Conv3d(3->16, 3x3x3, VALID) + bias + channel softmax + maxpool(4,4,4)/4.
// x: [512,3,16,32,32] f32, w: [16,3,3,3,3] f32, b: [16] f32
// out: [512,16,3,7,7] f32
//
// R7 = R5 block structure (one block per (n,pd,ph), 10752 blocks, 14 KB LDS,
// ~48% occupancy) + packed fp16 arithmetic (v_pk_fma_f16, 2 ch/instr):
//   - R6 regressed because its 34.8 KB LDS tile dropped occupancy to 20%.
//     Occupancy > per-block weight reuse on this kernel (R5 vs R6 evidence).
//   - inputs staged as PRE-SPLATTED half2 (4 B/elem, conflict-free b32 reads).
//   - weights fp16 [tap][c] in d_ws, uniform-address dwordx4 (vmcnt, L1-hot).
//   - acc[4][8] half2 = 32 VGPRs (was 64 fp32) -> stays in arch VGPRs.

#define LW 33  // lw stride in half2 units (+1: dh groups land on distinct banks)

__global__ void wtrans(const float* __restrict__ w, __half* __restrict__ wt) {
  for (int t = threadIdx.x; t < 81 * 16; t += 128) {
    int c = t & 15, tap = t >> 4;
    wt[t] = __float2half(w[c * 81 + tap]);  // wt[tap][c]
  }
}

__global__ __launch_bounds__(128) void conv_sm_pool(
    const float* __restrict__ x, const __half* __restrict__ wt,
    const float* __restrict__ b, float* __restrict__ out) {
  __shared__ __half2 xs[3 * 6 * 6 * LW];    // [cin][ld][lh][lw], splatted half2
  __shared__ float pool[7 * 16];            // [pw][c]

  const int tid = threadIdx.x;
  const int blk = blockIdx.x;
  const int n  = blk / 21;
  const int r  = blk % 21;
  const int pd = r / 7;
  const int ph = r % 7;

  // ---- stage input tile: cin 0..2, d 4pd..4pd+5, h 4ph..4ph+5, w 0..31 ----
  const float* xb = x + ((size_t)n * 3 * 16 * 32 * 32)
                      + (size_t)(4 * pd) * 32 * 32 + (size_t)(4 * ph) * 32;
  for (int i = tid; i < 3 * 6 * 6 * 16; i += 128) {  // float2 pairs
    int lw2 = i & 15;
    int rest = i >> 4;            // cin*36 + ld*6 + lh
    int lh = rest % 6;
    int rest2 = rest / 6;
    int ld = rest2 % 6;
    int cin = rest2 / 6;
    const float2 v = *reinterpret_cast<const float2*>(
        &xb[((cin * 16 + ld) * 32 + lh) * 32 + lw2 * 2]);
    __half2* dst = &xs[((cin * 6 + ld) * 6 + lh) * LW + lw2 * 2];
    dst[0] = __float2half2_rn(v.x);   // splat
    dst[1] = __float2half2_rn(v.y);
  }
  if (tid < 112) pool[tid] = 0.0f;    // softmax probs are > 0
  __syncthreads();

  if (tid < 112) {
    const int dh = tid / 28;      // conv h = 4*ph + dh
    const int wp = tid % 28;      // conv w

    __half2 acc[4][8];            // [d][channel-pair] = 32 VGPRs
#pragma unroll
    for (int c2 = 0; c2 < 8; ++c2) {
      __half2 bb = __halves2half2(__float2half(b[2 * c2]),
                                  __float2half(b[2 * c2 + 1]));
#pragma unroll
      for (int d = 0; d < 4; ++d) acc[d][c2] = bb;
    }

    const float4* wt4 = reinterpret_cast<const float4*>(wt);  // 8 half2/tap
    for (int cin = 0; cin < 3; ++cin) {
      for (int kh = 0; kh < 3; ++kh) {
        const __half2* xbase = &xs[((cin * 6) * 6 + dh + kh) * LW + wp];
        __half2 in[3][6];
#pragma unroll
        for (int kw = 0; kw < 3; ++kw)
#pragma unroll
          for (int ld = 0; ld < 6; ++ld)
            in[kw][ld] = xbase[(ld * 6) * LW + kw];   // immediate offsets

        const float4* wb = wt4 + (cin * 27 + kh * 3) * 2;
#pragma unroll
        for (int kw = 0; kw < 3; ++kw) {
#pragma unroll
          for (int kr = 0; kr < 3; ++kr) {
            float4 wv0 = wb[(kr * 9 + kw) * 2 + 0];   // ch 0..7, uniform addr
            float4 wv1 = wb[(kr * 9 + kw) * 2 + 1];   // ch 8..15
            const __half2* w0 = reinterpret_cast<const __half2*>(&wv0);
            const __half2* w1 = reinterpret_cast<const __half2*>(&wv1);
#pragma unroll
            for (int c2 = 0; c2 < 4; ++c2) {
#pragma unroll
              for (int d = 0; d < 4; ++d) {
                acc[d][c2]     = __hfma2(in[kw][d + kr], w0[c2], acc[d][c2]);
                acc[d][c2 + 4] = __hfma2(in[kw][d + kr], w1[c2], acc[d][c2 + 4]);
              }
            }
          }
        }
      }
    }

    // ---- softmax over 16 channels per d, then max over d ----
    float pm[16];
#pragma unroll
    for (int c = 0; c < 16; ++c) pm[c] = 0.0f;
#pragma unroll
    for (int d = 0; d < 4; ++d) {
      float y[16];
#pragma unroll
      for (int c2 = 0; c2 < 8; ++c2) {
        float2 f = __half22float2(acc[d][c2]);
        y[2 * c2] = f.x; y[2 * c2 + 1] = f.y;
      }
      float m = y[0];
#pragma unroll
      for (int c = 1; c < 16; ++c) m = fmaxf(m, y[c]);
      float s = 0.0f;
#pragma unroll
      for (int c = 0; c < 16; ++c) { y[c] = __expf(y[c] - m); s += y[c]; }
      float rs = 1.0f / s;
#pragma unroll
      for (int c = 0; c < 16; ++c) pm[c] = fmaxf(pm[c], y[c] * rs);
    }

    // ---- pooled max: shuffle-reduce 4 w-lanes, then LDS atomic ----
    // lane%4 == wp%4 in both waves (28%4==0, 64%4==0).
#pragma unroll
    for (int c = 0; c < 16; ++c) {
      pm[c] = fmaxf(pm[c], __shfl_xor(pm[c], 1, 64));
      pm[c] = fmaxf(pm[c], __shfl_xor(pm[c], 2, 64));
    }
    if ((wp & 3) == 0) {
      const int pw = wp >> 2;
#pragma unroll
      for (int c = 0; c < 16; ++c)
        atomicMax(reinterpret_cast<int*>(&pool[pw * 16 + c]),
                  __float_as_int(pm[c]));  // probs > 0
    }
  }
  __syncthreads();

  if (tid < 112) {
    int c = tid / 7, pw = tid % 7;
    out[(((size_t)n * 16 + c) * 3 + pd) * 49 + (size_t)ph * 7 + pw] =
        pool[pw * 16 + c];
  }
}

extern "C" void kernel_launch(void* const* d_in, const int* in_sizes, int n_in,
                              void* d_out, int out_size, void* d_ws, size_t ws_size,
                              hipStream_t stream) {
  const float* x = (const float*)d_in[0];
  const float* w = (const float*)d_in[1];
  const float* b = (const float*)d_in[2];
  float* out = (float*)d_out;
  __half* wtp = (__half*)d_ws;   // 81*16*2 = 2592 B scratch
  (void)in_sizes; (void)n_in; (void)out_size; (void)ws_size;
  hipLaunchKernelGGL(wtrans, dim3(1), dim3(128), 0, stream, w, wtp);
  hipLaunchKernelGGL(conv_sm_pool, dim3(512 * 3 * 7), dim3(128), 0, stream,
                     x, wtp, b, out);
}

// Round 8
// 284.532 us; speedup vs baseline: 1.1480x; 1.0023x over previous
//
#include <hip/hip_runtime.h>
#include <hip/hip_fp16.h>

// Fused Conv3d(3->16, 3x3x3, VALID) + bias + channel softmax + maxpool(4,4,4)/4.
// x: [512,3,16,32,32] f32, w: [16,3,3,3,3] f32, b: [16] f32
// out: [512,16,3,7,7] f32
//
// R8 = R7 + __launch_bounds__(128, 4).
// R7 post-mortem: halving FMA count gave only -8% => FMA issue not binding.
// VGPR_Count=40 with a ~90-reg live set means the compiler capped arch VGPRs
// for 8-waves/SIMD occupancy and round-trips the accumulators through AGPRs
// (we're LDS-limited to ~5 blocks/CU = ~10 waves anyway, so that occupancy
// does not exist). (128,4) => 4 waves/EU target => 128-VGPR cap: acc + in +
// weights stay in arch VGPRs, long load->use distance, no AGPR moves.

#define LW 33  // lw stride in half2 units (+1: dh groups land on distinct banks)

__global__ void wtrans(const float* __restrict__ w, __half* __restrict__ wt) {
  for (int t = threadIdx.x; t < 81 * 16; t += 128) {
    int c = t & 15, tap = t >> 4;
    wt[t] = __float2half(w[c * 81 + tap]);  // wt[tap][c]
  }
}

__global__ __launch_bounds__(128, 4) void conv_sm_pool(
    const float* __restrict__ x, const __half* __restrict__ wt,
    const float* __restrict__ b, float* __restrict__ out) {
  __shared__ __half2 xs[3 * 6 * 6 * LW];    // [cin][ld][lh][lw], splatted half2
  __shared__ float pool[7 * 16];            // [pw][c]

  const int tid = threadIdx.x;
  const int blk = blockIdx.x;
  const int n  = blk / 21;
  const int r  = blk % 21;
  const int pd = r / 7;
  const int ph = r % 7;

  // ---- stage input tile: cin 0..2, d 4pd..4pd+5, h 4ph..4ph+5, w 0..31 ----
  const float* xb = x + ((size_t)n * 3 * 16 * 32 * 32)
                      + (size_t)(4 * pd) * 32 * 32 + (size_t)(4 * ph) * 32;
  for (int i = tid; i < 3 * 6 * 6 * 16; i += 128) {  // float2 pairs
    int lw2 = i & 15;
    int rest = i >> 4;            // cin*36 + ld*6 + lh
    int lh = rest % 6;
    int rest2 = rest / 6;
    int ld = rest2 % 6;
    int cin = rest2 / 6;
    const float2 v = *reinterpret_cast<const float2*>(
        &xb[((cin * 16 + ld) * 32 + lh) * 32 + lw2 * 2]);
    __half2* dst = &xs[((cin * 6 + ld) * 6 + lh) * LW + lw2 * 2];
    dst[0] = __float2half2_rn(v.x);   // splat
    dst[1] = __float2half2_rn(v.y);
  }
  if (tid < 112) pool[tid] = 0.0f;    // softmax probs are > 0
  __syncthreads();

  if (tid < 112) {
    const int dh = tid / 28;      // conv h = 4*ph + dh
    const int wp = tid % 28;      // conv w

    __half2 acc[4][8];            // [d][channel-pair] = 32 VGPRs
#pragma unroll
    for (int c2 = 0; c2 < 8; ++c2) {
      __half2 bb = __halves2half2(__float2half(b[2 * c2]),
                                  __float2half(b[2 * c2 + 1]));
#pragma unroll
      for (int d = 0; d < 4; ++d) acc[d][c2] = bb;
    }

    const float4* wt4 = reinterpret_cast<const float4*>(wt);  // 8 half2/tap
    for (int cin = 0; cin < 3; ++cin) {
      for (int kh = 0; kh < 3; ++kh) {
        const __half2* xbase = &xs[((cin * 6) * 6 + dh + kh) * LW + wp];
        __half2 in[3][6];
#pragma unroll
        for (int kw = 0; kw < 3; ++kw)
#pragma unroll
          for (int ld = 0; ld < 6; ++ld)
            in[kw][ld] = xbase[(ld * 6) * LW + kw];   // immediate offsets

        const float4* wb = wt4 + (cin * 27 + kh * 3) * 2;
#pragma unroll
        for (int kw = 0; kw < 3; ++kw) {
#pragma unroll
          for (int kr = 0; kr < 3; ++kr) {
            float4 wv0 = wb[(kr * 9 + kw) * 2 + 0];   // ch 0..7, uniform addr
            float4 wv1 = wb[(kr * 9 + kw) * 2 + 1];   // ch 8..15
            const __half2* w0 = reinterpret_cast<const __half2*>(&wv0);
            const __half2* w1 = reinterpret_cast<const __half2*>(&wv1);
#pragma unroll
            for (int c2 = 0; c2 < 4; ++c2) {
#pragma unroll
              for (int d = 0; d < 4; ++d) {
                acc[d][c2]     = __hfma2(in[kw][d + kr], w0[c2], acc[d][c2]);
                acc[d][c2 + 4] = __hfma2(in[kw][d + kr], w1[c2], acc[d][c2 + 4]);
              }
            }
          }
        }
      }
    }

    // ---- softmax over 16 channels per d, then max over d ----
    float pm[16];
#pragma unroll
    for (int c = 0; c < 16; ++c) pm[c] = 0.0f;
#pragma unroll
    for (int d = 0; d < 4; ++d) {
      float y[16];
#pragma unroll
      for (int c2 = 0; c2 < 8; ++c2) {
        float2 f = __half22float2(acc[d][c2]);
        y[2 * c2] = f.x; y[2 * c2 + 1] = f.y;
      }
      float m = y[0];
#pragma unroll
      for (int c = 1; c < 16; ++c) m = fmaxf(m, y[c]);
      float s = 0.0f;
#pragma unroll
      for (int c = 0; c < 16; ++c) { y[c] = __expf(y[c] - m); s += y[c]; }
      float rs = 1.0f / s;
#pragma unroll
      for (int c = 0; c < 16; ++c) pm[c] = fmaxf(pm[c], y[c] * rs);
    }

    // ---- pooled max: shuffle-reduce 4 w-lanes, then LDS atomic ----
    // lane%4 == wp%4 in both waves (28%4==0, 64%4==0).
#pragma unroll
    for (int c = 0; c < 16; ++c) {
      pm[c] = fmaxf(pm[c], __shfl_xor(pm[c], 1, 64));
      pm[c] = fmaxf(pm[c], __shfl_xor(pm[c], 2, 64));
    }
    if ((wp & 3) == 0) {
      const int pw = wp >> 2;
#pragma unroll
      for (int c = 0; c < 16; ++c)
        atomicMax(reinterpret_cast<int*>(&pool[pw * 16 + c]),
                  __float_as_int(pm[c]));  // probs > 0
    }
  }
  __syncthreads();

  if (tid < 112) {
    int c = tid / 7, pw = tid % 7;
    out[(((size_t)n * 16 + c) * 3 + pd) * 49 + (size_t)ph * 7 + pw] =
        pool[pw * 16 + c];
  }
}

extern "C" void kernel_launch(void* const* d_in, const int* in_sizes, int n_in,
                              void* d_out, int out_size, void* d_ws, size_t ws_size,
                              hipStream_t stream) {
  const float* x = (const float*)d_in[0];
  const float* w = (const float*)d_in[1];
  const float* b = (const float*)d_in[2];
  float* out = (float*)d_out;
  __half* wtp = (__half*)d_ws;   // 81*16*2 = 2592 B scratch
  (void)in_sizes; (void)n_in; (void)out_size; (void)ws_size;
  hipLaunchKernelGGL(wtrans, dim3(1), dim3(128), 0, stream, w, wtp);
  hipLaunchKernelGGL(conv_sm_pool, dim3(512 * 3 * 7), dim3(128), 0, stream,
                     x, wtp, b, out);
}

// Round 9
// 281.726 us; speedup vs baseline: 1.1594x; 1.0100x over previous
//
#include <hip/hip_runtime.h>
#include <hip/hip_fp16.h>

// Fused Conv3d(3->16, 3x3x3, VALID) + bias + channel softmax + maxpool(4,4,4)/4.
// x: [512,3,16,32,32] f32, w: [16,3,3,3,3] f32, b: [16] f32
// out: [512,16,3,7,7] f32
//
// R9 = R8 with the weight stream moved from per-wave VMEM to LDS broadcast.
// Evidence: dur invariant (197/182/184) to halved FMA and to reg knobs; the
// constant across rounds is 162 uniform-address global_load_dwordx4 per wave
// (weight refetch, ~16cyc/instr on the VMEM return path ~= 91us/CU) + 162
// ds_read_b32 input reads. This round: weights fp16 [tap][c] staged once per
// block into LDS (2.6 KB), inner loop reads 18 ds_read_b128 broadcasts per
// (cin,kh) iter. No vmcnt waits remain in the K-loop.

#define LW 33  // lw stride in half2 units (+1: dh groups land on distinct banks)

__global__ void wtrans(const float* __restrict__ w, __half* __restrict__ wt) {
  for (int t = threadIdx.x; t < 81 * 16; t += 128) {
    int c = t & 15, tap = t >> 4;
    wt[t] = __float2half(w[c * 81 + tap]);  // wt[tap][c]
  }
}

__global__ __launch_bounds__(128, 4) void conv_sm_pool(
    const float* __restrict__ x, const __half* __restrict__ wt,
    const float* __restrict__ b, float* __restrict__ out) {
  __shared__ __half2 xs[3 * 6 * 6 * LW];       // [cin][ld][lh][lw], splatted half2
  __shared__ __align__(16) __half wl[81 * 16]; // [tap][c], 2592 B
  __shared__ float pool[7 * 16];               // [pw][c]

  const int tid = threadIdx.x;
  const int blk = blockIdx.x;
  const int n  = blk / 21;
  const int r  = blk % 21;
  const int pd = r / 7;
  const int ph = r % 7;

  // ---- stage weights: 648 dwords, coalesced from d_ws ----
  {
    const int* src = reinterpret_cast<const int*>(wt);
    int* dst = reinterpret_cast<int*>(wl);
    for (int i = tid; i < 81 * 16 / 2; i += 128) dst[i] = src[i];
  }

  // ---- stage input tile: cin 0..2, d 4pd..4pd+5, h 4ph..4ph+5, w 0..31 ----
  const float* xb = x + ((size_t)n * 3 * 16 * 32 * 32)
                      + (size_t)(4 * pd) * 32 * 32 + (size_t)(4 * ph) * 32;
  for (int i = tid; i < 3 * 6 * 6 * 16; i += 128) {  // float2 pairs
    int lw2 = i & 15;
    int rest = i >> 4;            // cin*36 + ld*6 + lh
    int lh = rest % 6;
    int rest2 = rest / 6;
    int ld = rest2 % 6;
    int cin = rest2 / 6;
    const float2 v = *reinterpret_cast<const float2*>(
        &xb[((cin * 16 + ld) * 32 + lh) * 32 + lw2 * 2]);
    __half2* dst = &xs[((cin * 6 + ld) * 6 + lh) * LW + lw2 * 2];
    dst[0] = __float2half2_rn(v.x);   // splat
    dst[1] = __float2half2_rn(v.y);
  }
  if (tid < 112) pool[tid] = 0.0f;    // softmax probs are > 0
  __syncthreads();

  if (tid < 112) {
    const int dh = tid / 28;      // conv h = 4*ph + dh
    const int wp = tid % 28;      // conv w

    __half2 acc[4][8];            // [d][channel-pair] = 32 VGPRs
#pragma unroll
    for (int c2 = 0; c2 < 8; ++c2) {
      __half2 bb = __halves2half2(__float2half(b[2 * c2]),
                                  __float2half(b[2 * c2 + 1]));
#pragma unroll
      for (int d = 0; d < 4; ++d) acc[d][c2] = bb;
    }

    const float4* wl4 = reinterpret_cast<const float4*>(wl);  // 2 float4/tap
    for (int cin = 0; cin < 3; ++cin) {
      for (int kh = 0; kh < 3; ++kh) {
        const __half2* xbase = &xs[((cin * 6) * 6 + dh + kh) * LW + wp];
        __half2 in[3][6];
#pragma unroll
        for (int kw = 0; kw < 3; ++kw)
#pragma unroll
          for (int ld = 0; ld < 6; ++ld)
            in[kw][ld] = xbase[(ld * 6) * LW + kw];   // immediate offsets

        const int tbase = cin * 27 + kh * 3;
#pragma unroll
        for (int kw = 0; kw < 3; ++kw) {
#pragma unroll
          for (int kr = 0; kr < 3; ++kr) {
            // same-address across the wave -> LDS broadcast, conflict-free
            float4 wv0 = wl4[(tbase + kr * 9 + kw) * 2 + 0];  // ch 0..7
            float4 wv1 = wl4[(tbase + kr * 9 + kw) * 2 + 1];  // ch 8..15
            const __half2* w0 = reinterpret_cast<const __half2*>(&wv0);
            const __half2* w1 = reinterpret_cast<const __half2*>(&wv1);
#pragma unroll
            for (int c2 = 0; c2 < 4; ++c2) {
#pragma unroll
              for (int d = 0; d < 4; ++d) {
                acc[d][c2]     = __hfma2(in[kw][d + kr], w0[c2], acc[d][c2]);
                acc[d][c2 + 4] = __hfma2(in[kw][d + kr], w1[c2], acc[d][c2 + 4]);
              }
            }
          }
        }
      }
    }

    // ---- softmax over 16 channels per d, then max over d ----
    float pm[16];
#pragma unroll
    for (int c = 0; c < 16; ++c) pm[c] = 0.0f;
#pragma unroll
    for (int d = 0; d < 4; ++d) {
      float y[16];
#pragma unroll
      for (int c2 = 0; c2 < 8; ++c2) {
        float2 f = __half22float2(acc[d][c2]);
        y[2 * c2] = f.x; y[2 * c2 + 1] = f.y;
      }
      float m = y[0];
#pragma unroll
      for (int c = 1; c < 16; ++c) m = fmaxf(m, y[c]);
      float s = 0.0f;
#pragma unroll
      for (int c = 0; c < 16; ++c) { y[c] = __expf(y[c] - m); s += y[c]; }
      float rs = 1.0f / s;
#pragma unroll
      for (int c = 0; c < 16; ++c) pm[c] = fmaxf(pm[c], y[c] * rs);
    }

    // ---- pooled max: shuffle-reduce 4 w-lanes, then LDS atomic ----
    // lane%4 == wp%4 in both waves (28%4==0, 64%4==0).
#pragma unroll
    for (int c = 0; c < 16; ++c) {
      pm[c] = fmaxf(pm[c], __shfl_xor(pm[c], 1, 64));
      pm[c] = fmaxf(pm[c], __shfl_xor(pm[c], 2, 64));
    }
    if ((wp & 3) == 0) {
      const int pw = wp >> 2;
#pragma unroll
      for (int c = 0; c < 16; ++c)
        atomicMax(reinterpret_cast<int*>(&pool[pw * 16 + c]),
                  __float_as_int(pm[c]));  // probs > 0
    }
  }
  __syncthreads();

  if (tid < 112) {
    int c = tid / 7, pw = tid % 7;
    out[(((size_t)n * 16 + c) * 3 + pd) * 49 + (size_t)ph * 7 + pw] =
        pool[pw * 16 + c];
  }
}

extern "C" void kernel_launch(void* const* d_in, const int* in_sizes, int n_in,
                              void* d_out, int out_size, void* d_ws, size_t ws_size,
                              hipStream_t stream) {
  const float* x = (const float*)d_in[0];
  const float* w = (const float*)d_in[1];
  const float* b = (const float*)d_in[2];
  float* out = (float*)d_out;
  __half* wtp = (__half*)d_ws;   // 81*16*2 = 2592 B scratch
  (void)in_sizes; (void)n_in; (void)out_size; (void)ws_size;
  hipLaunchKernelGGL(wtrans, dim3(1), dim3(128), 0, stream, w, wtp);
  hipLaunchKernelGGL(conv_sm_pool, dim3(512 * 3 * 7), dim3(128), 0, stream,
                     x, wtp, b, out);
}

// Round 10
// 239.516 us; speedup vs baseline: 1.3638x; 1.1762x over previous
//
#include <hip/hip_runtime.h>
#include <hip/hip_fp16.h>

// Fused Conv3d(3->16, 3x3x3, VALID) + bias + channel softmax + maxpool(4,4,4)/4.
// x: [512,3,16,32,32] f32, w: [16,3,3,3,3] f32, b: [16] f32 -> out [512,16,3,7,7] f32
//
// R10: MFMA implicit GEMM. Per block (n,pd,ph): D[c][pos] = sum_k W[c][k] X[k][pos],
// M=16 ch, N=448 pos (dd,dh,wp), K=112 (81 taps padded in groups of 4: (cin,kd,kh) x kw0..2,pad).
// mfma_f32_16x16x32_f16, fp32 accum. A=weights (frag-ready in d_ws, zero-padded).
// B=x gathered from LDS: lane's 4 consecutive k are w-contiguous -> 2 adjacent dwords;
// parity-duplicated xs copy makes every lane 4B-aligned (wp parity == lane parity).
// Softmax across lane-groups (shfl_xor 16/32), max-sub skipped (|y|<=~2.5).
// Pool: dd-pair in-lane, wp-quad shfl_xor(1/2), one b128 write per slot (no atomics).

typedef _Float16 half8 __attribute__((ext_vector_type(8)));
typedef float f32x4 __attribute__((ext_vector_type(4)));
union H8 { int4 i; half8 h; };

// Build frag-ready weights: wsA[v][lane] = 8 halves A[c=lane&15][k=32v+8(lane>>4)+j].
// tap group G = k>>2 = 8v+2g+(j>>2), kw = k&3; zero for G>=27 or kw==3.
__global__ void wtrans(const float* __restrict__ w, int4* __restrict__ wsA) {
  int t = threadIdx.x;            // 256 threads: v = t>>6, lane = t&63
  int v = t >> 6, l = t & 63;
  int c = l & 15, g = l >> 4;
  unsigned hh[8];
  for (int j = 0; j < 8; ++j) {
    int G = 8 * v + 2 * g + (j >> 2);
    int kw = j & 3;
    float val = (G < 27 && kw < 3) ? w[c * 81 + G * 3 + kw] : 0.0f;
    __half h = __float2half(val);
    hh[j] = (unsigned)__half_as_ushort(h);
  }
  int4 o;
  o.x = (int)(hh[0] | (hh[1] << 16));
  o.y = (int)(hh[2] | (hh[3] << 16));
  o.z = (int)(hh[4] | (hh[5] << 16));
  o.w = (int)(hh[6] | (hh[7] << 16));
  wsA[v * 64 + l] = o;
}

__global__ __launch_bounds__(128) void conv_sm_pool(
    const float* __restrict__ x, const int4* __restrict__ wsA,
    const float* __restrict__ b, float* __restrict__ out) {
  __shared__ int xs32[1728];    // x tile as half pairs: [cin][ld0..5][lh0..5][lw0..31]
  __shared__ int dup32[1728];   // shifted-by-one-half copy: dup[i] = halves(2i+1, 2i+2)
  __shared__ float pool2[896];  // [wv*4+dh][pw][c] = 8*7*16

  const int tid = threadIdx.x;
  const int blk = blockIdx.x;
  const int n = blk / 21, rr = blk % 21, pd = rr / 7, ph = rr % 7;

  // ---- stage x tile as fp16 pairs ----
  const float* xb = x + ((size_t)n * 3 * 16 * 32 * 32)
                  + (size_t)(4 * pd) * 1024 + (size_t)(4 * ph) * 32;
  for (int i = tid; i < 1728; i += 128) {
    int lw2 = i & 15;
    int rest = i >> 4;          // cin*36 + ld*6 + lh
    int lh = rest % 6, rest2 = rest / 6, ld = rest2 % 6, cin = rest2 / 6;
    float2 v = *reinterpret_cast<const float2*>(
        &xb[((cin * 16 + ld) * 32 + lh) * 32 + lw2 * 2]);
    __half2 h2 = __float22half2_rn(v);
    xs32[i] = *reinterpret_cast<int*>(&h2);
  }
  __syncthreads();
  // ---- shifted duplicate for odd-parity lanes ----
  for (int i = tid; i < 1728; i += 128) {
    int nxt = (i < 1727) ? xs32[i + 1] : 0;
    dup32[i] = (int)(((unsigned)xs32[i] >> 16) | ((unsigned)nxt << 16));
  }
  __syncthreads();

  const int lane = tid & 63, wv = tid >> 6;
  const int l15 = lane & 15, g = lane >> 4;
  const int par = l15 & 1;
  const int* bas = par ? dup32 : xs32;

  // A-frags (weights), held in regs
  H8 wa[4];
#pragma unroll
  for (int v = 0; v < 4; ++v) wa[v].i = wsA[v * 64 + lane];

  // tap-group half-offsets per window (two groups of 4 taps per lane per window)
  int TH0[4], TH1[4];
#pragma unroll
  for (int v = 0; v < 4; ++v) {
    int G0 = 8 * v + 2 * g, G1 = G0 + 1;
    if (G0 > 26) G0 = 26;
    if (G1 > 26) G1 = 26;
    int c0 = G0 / 9, r0 = G0 % 9, c1 = G1 / 9, r1 = G1 % 9;
    TH0[v] = (c0 * 1152 + (r0 / 3) * 192 + (r0 % 3) * 32) >> 1;
    TH1[v] = (c1 * 1152 + (r1 / 3) * 192 + (r1 % 3) * 32) >> 1;
  }

  // position half-offsets per N-tile: P = dd*192 + dh*32 + wp, PH = (P-par)>>1
  int PH[14];
#pragma unroll
  for (int tl = 0; tl < 14; ++tl) {
    int m0 = (wv * 14 + tl) * 16;
    int dd = m0 / 112;
    int rem112 = m0 % 112;
    int dhc = rem112 / 28, rem28 = rem112 % 28;
    int bump = (rem28 + l15) >= 28 ? 1 : 0;
    int P = dd * 192 + (dhc + bump) * 32 + (rem28 + l15 - 28 * bump);
    PH[tl] = (P - par) >> 1;
  }

  // acc init with bias (row = channel = 4g+r)
  f32x4 acc[14];
  float4 b4 = *reinterpret_cast<const float4*>(b + 4 * g);
  f32x4 binit;
  binit[0] = b4.x; binit[1] = b4.y; binit[2] = b4.z; binit[3] = b4.w;
#pragma unroll
  for (int tl = 0; tl < 14; ++tl) acc[tl] = binit;

  // ---- main: 4 K-windows x 14 N-tiles ----
#pragma unroll
  for (int v = 0; v < 4; ++v) {
#pragma unroll
    for (int tl = 0; tl < 14; ++tl) {
      int o0 = PH[tl] + TH0[v];
      int o1 = PH[tl] + TH1[v];
      H8 bf;
      bf.i.x = bas[o0];
      bf.i.y = bas[o0 + 1];
      bf.i.z = bas[o1];
      bf.i.w = bas[o1 + 1];
      acc[tl] = __builtin_amdgcn_mfma_f32_16x16x32_f16(wa[v].h, bf.h, acc[tl], 0, 0, 0);
    }
  }

  // ---- epilogue: softmax over channels (cross lane-group), pool ----
  // lane holds channels 4g..4g+3 at position pos = l15 + 16*(wv*14+tl)
#pragma unroll
  for (int tp = 0; tp < 7; ++tp) {
    float pm[4];
#pragma unroll
    for (int hf = 0; hf < 2; ++hf) {
      int tl = tp + 7 * hf;       // tiles tp and tp+7: same (dh,wp), dd differs
      float e[4];
#pragma unroll
      for (int q = 0; q < 4; ++q) e[q] = __expf(acc[tl][q]);
      float s = (e[0] + e[1]) + (e[2] + e[3]);
      s += __shfl_xor(s, 16, 64);
      s += __shfl_xor(s, 32, 64);
      float rs = __builtin_amdgcn_rcpf(s);
      if (hf == 0) {
#pragma unroll
        for (int q = 0; q < 4; ++q) pm[q] = e[q] * rs;
      } else {
#pragma unroll
        for (int q = 0; q < 4; ++q) pm[q] = fmaxf(pm[q], e[q] * rs);
      }
    }
    // wp-quad reduce (l15 quads are exact wp quads, same (dd,dh))
#pragma unroll
    for (int q = 0; q < 4; ++q) {
      pm[q] = fmaxf(pm[q], __shfl_xor(pm[q], 1, 64));
      pm[q] = fmaxf(pm[q], __shfl_xor(pm[q], 2, 64));
    }
    if ((l15 & 3) == 0) {
      int m0 = (wv * 14 + tp) * 16;
      int rem112 = m0 % 112;
      int dhc = rem112 / 28, rem28 = rem112 % 28;
      int bump = (rem28 + l15) >= 28 ? 1 : 0;
      int dh = dhc + bump;
      int pw = (rem28 + l15 - 28 * bump) >> 2;
      float4 val = {pm[0], pm[1], pm[2], pm[3]};
      *reinterpret_cast<float4*>(&pool2[(((wv * 4 + dh) * 7 + pw) << 4) + 4 * g]) = val;
    }
  }
  __syncthreads();

  if (tid < 112) {
    int c = tid / 7, pw = tid % 7;
    float m = pool2[((pw) << 4) + c];
#pragma unroll
    for (int s = 1; s < 8; ++s)
      m = fmaxf(m, pool2[(((s * 7 + pw)) << 4) + c]);
    out[(((size_t)n * 16 + c) * 3 + pd) * 49 + (size_t)ph * 7 + pw] = m;
  }
}

extern "C" void kernel_launch(void* const* d_in, const int* in_sizes, int n_in,
                              void* d_out, int out_size, void* d_ws, size_t ws_size,
                              hipStream_t stream) {
  const float* x = (const float*)d_in[0];
  const float* w = (const float*)d_in[1];
  const float* b = (const float*)d_in[2];
  float* out = (float*)d_out;
  int4* wsA = (int4*)d_ws;   // 4 windows * 64 lanes * 16 B = 4096 B
  (void)in_sizes; (void)n_in; (void)out_size; (void)ws_size;
  hipLaunchKernelGGL(wtrans, dim3(1), dim3(256), 0, stream, w, wsA);
  hipLaunchKernelGGL(conv_sm_pool, dim3(512 * 3 * 7), dim3(128), 0, stream,
                     x, wsA, b, out);
}